// Round 5
// baseline (448.610 us; speedup 1.0000x reference)
//
#include <hip/hip_runtime.h>

#define B_ 8
#define T_ 1024
#define D_ 256
#define NBAND 7
#define MROWS (B_*T_)             // 8192 rows per band
#define BAND_ELEMS (MROWS*D_)     // 2097152

typedef __attribute__((ext_vector_type(8))) short bf16x8;
typedef __attribute__((ext_vector_type(4))) float f32x4;

__device__ __forceinline__ unsigned short f2bf(float f) {
  unsigned int u = __float_as_uint(f);
  u = u + 0x7fffu + ((u >> 16) & 1u);
  return (unsigned short)(u >> 16);
}
__device__ __forceinline__ float bf2f(unsigned short h) {
  return __uint_as_float(((unsigned int)h) << 16);
}

// ---------------- conversion fp32 -> bf16 ----------------
struct CvtSeg { const float* src; unsigned short* dst; int n; };
struct CvtParams { CvtSeg seg[14]; };

__global__ __launch_bounds__(256) void cvt_kernel(CvtParams p) {
  CvtSeg s = p.seg[blockIdx.y];
  int i = (blockIdx.x * 256 + threadIdx.x) * 4;
  if (i >= s.n) return;
  float4 v = *(const float4*)(s.src + i);
  ushort4 o;
  o.x = f2bf(v.x); o.y = f2bf(v.y); o.z = f2bf(v.z); o.w = f2bf(v.w);
  *(ushort4*)(s.dst + i) = o;
}

// ============ wide GEMM core: block tile 128 rows x 256 cols (full N) =======
// 4 waves in 2x2; wave tile 64x128 = acc[4][8]. Per ki (BK=64): stage A 16KB
// (once for ALL 256 cols) + W 32KB, then 64 MFMAs/wave between barrier pairs.
// LDS granule g (16B) of row r stored at slot g^(r&7) (conflict-free frags;
// global_load_lds dest = wave base + lane*16 HW constraint).
template<int NKI, bool TWOA>
__device__ __forceinline__ void gemm_wide(const unsigned short* __restrict__ Aa,
                                          const unsigned short* __restrict__ Ab,
                                          const unsigned short* __restrict__ W,
                                          int m0,
                                          unsigned short* a_lds,   // 128*64
                                          unsigned short* w_lds,   // 256*64
                                          f32x4 acc[4][8]) {
  const int lane = threadIdx.x & 63, wv = threadIdx.x >> 6;
  const int quad = lane >> 4, l15 = lane & 15;
  const int lrow = lane >> 3;           // 0..7
  const int gsw  = (lane & 7) ^ lrow;   // swizzled global granule for this lane
  const int arow0 = (wv >> 1) * 64 + l15;
  const int wrow0 = (wv & 1) * 128 + l15;
  const int s7 = l15 & 7;
  const int KW = NKI * 64;

#pragma unroll
  for (int ki = 0; ki < NKI; ++ki) {
    const unsigned short* Asrc = (TWOA && ki >= NKI / 2) ? Ab : Aa;
    const int kk = (TWOA && ki >= NKI / 2) ? (ki - NKI / 2) * 64 : ki * 64;
    // A: 128 rows x 64 k; wave stages rows p*32 + wv*8 (+lrow)
#pragma unroll
    for (int p = 0; p < 4; ++p) {
      const int r = p * 32 + wv * 8;
      const unsigned short* gp = Asrc + (size_t)(m0 + r + lrow) * 256 + kk + gsw * 8;
      unsigned short* lp = a_lds + r * 64;
      __builtin_amdgcn_global_load_lds((const __attribute__((address_space(1))) void*)gp,
                                       (__attribute__((address_space(3))) void*)lp, 16, 0, 0);
    }
    // W: 256 rows x 64 k
#pragma unroll
    for (int p = 0; p < 8; ++p) {
      const int r = p * 32 + wv * 8;
      const unsigned short* gp = W + (size_t)(r + lrow) * KW + ki * 64 + gsw * 8;
      unsigned short* lp = w_lds + r * 64;
      __builtin_amdgcn_global_load_lds((const __attribute__((address_space(1))) void*)gp,
                                       (__attribute__((address_space(3))) void*)lp, 16, 0, 0);
    }
    __syncthreads();
#pragma unroll
    for (int kc = 0; kc < 2; ++kc) {
      const int s = ((kc * 4 + quad) ^ s7) * 8;
      bf16x8 af[4], wf[8];
#pragma unroll
      for (int rt = 0; rt < 4; ++rt)
        af[rt] = *(const bf16x8*)(a_lds + (arow0 + rt * 16) * 64 + s);
#pragma unroll
      for (int ct = 0; ct < 8; ++ct)
        wf[ct] = *(const bf16x8*)(w_lds + (wrow0 + ct * 16) * 64 + s);
#pragma unroll
      for (int rt = 0; rt < 4; ++rt)
#pragma unroll
        for (int ct = 0; ct < 8; ++ct)
          acc[rt][ct] = __builtin_amdgcn_mfma_f32_16x16x32_bf16(af[rt], wf[ct], acc[rt][ct], 0, 0, 0);
    }
    __syncthreads();
  }
}

// ---------------- Q/K/V projection: z = n*3+which ----------------
struct ProjParams {
  const unsigned short* bands;   // [7][8192][256]
  const unsigned short* w[3];    // each [7][256][256]
  const float* bias[3];          // each [7][256] fp32
  unsigned short* dst[3];        // q,k,v [7][8192][256]
};
__global__ __launch_bounds__(256) void proj_kernel(ProjParams p) {
  __shared__ unsigned short a_lds[128 * 64];
  __shared__ unsigned short w_lds[256 * 64];
  const int z = blockIdx.z;
  const int n = z / 3, which = z % 3;
  const unsigned short* A = p.bands + n * BAND_ELEMS;
  const unsigned short* W = p.w[which] + n * D_ * D_;
  const float* bias = p.bias[which] + n * D_;
  unsigned short* Dst = p.dst[which] + n * BAND_ELEMS;
  const int m0 = blockIdx.x * 128;

  f32x4 acc[4][8];
#pragma unroll
  for (int i = 0; i < 4; ++i)
#pragma unroll
    for (int j = 0; j < 8; ++j) acc[i][j] = (f32x4){0.f, 0.f, 0.f, 0.f};
  gemm_wide<4, false>(A, A, W, m0, a_lds, w_lds, acc);

  const int lane = threadIdx.x & 63, wv = threadIdx.x >> 6;
  const int quad = lane >> 4, l15 = lane & 15;
  const int rowbase = m0 + (wv >> 1) * 64 + quad * 4;
  const int colbase = (wv & 1) * 128;
#pragma unroll
  for (int ct = 0; ct < 8; ++ct) {
    const int col = colbase + ct * 16 + l15;
    const float b = bias[col];
#pragma unroll
    for (int rt = 0; rt < 4; ++rt)
#pragma unroll
      for (int r = 0; r < 4; ++r)
        Dst[(size_t)(rowbase + rt * 16 + r) * 256 + col] = f2bf(acc[rt][ct][r] + b);
  }
}

// ---------------- inject projections (cross / crossr / bridge), z = band ----
struct InjParams {
  const unsigned short* src[7];
  const unsigned short* w[7];
  const float* bias[7];
  unsigned short* inject;
};
__global__ __launch_bounds__(256) void inject_kernel(InjParams p) {
  __shared__ unsigned short a_lds[128 * 64];
  __shared__ unsigned short w_lds[256 * 64];
  const int i = blockIdx.z;
  const unsigned short* A = p.src[i];
  const unsigned short* W = p.w[i];
  const float* bias = p.bias[i];
  unsigned short* Dst = p.inject + i * BAND_ELEMS;
  const int m0 = blockIdx.x * 128;

  f32x4 acc[4][8];
#pragma unroll
  for (int a = 0; a < 4; ++a)
#pragma unroll
    for (int b = 0; b < 8; ++b) acc[a][b] = (f32x4){0.f, 0.f, 0.f, 0.f};
  gemm_wide<4, false>(A, A, W, m0, a_lds, w_lds, acc);

  const int lane = threadIdx.x & 63, wv = threadIdx.x >> 6;
  const int quad = lane >> 4, l15 = lane & 15;
  const int rowbase = m0 + (wv >> 1) * 64 + quad * 4;
  const int colbase = (wv & 1) * 128;
#pragma unroll
  for (int ct = 0; ct < 8; ++ct) {
    const int col = colbase + ct * 16 + l15;
    const float b = bias[col];
#pragma unroll
    for (int rt = 0; rt < 4; ++rt)
#pragma unroll
      for (int r = 0; r < 4; ++r)
        Dst[(size_t)(rowbase + rt * 16 + r) * 256 + col] = f2bf(acc[rt][ct][r] + b);
  }
}

// ---------------- gate + output: K=512 (band | inject) ----------------
struct GateParams {
  const unsigned short* bands;   // bf16 [7][8192][256]
  const unsigned short* inject;  // bf16 [7][8192][256]
  const unsigned short* gatew;   // bf16 [7][256][512]
  const float* gateb;            // fp32 [7][256]
  const float* bandf[7];         // original fp32 bands
  float* out;                    // [7][8192][256]
};
__global__ __launch_bounds__(256) void gate_kernel(GateParams p) {
  __shared__ unsigned short a_lds[128 * 64];
  __shared__ unsigned short w_lds[256 * 64];
  const int i = blockIdx.z;
  const unsigned short* A0 = p.bands + i * BAND_ELEMS;
  const unsigned short* A1 = p.inject + i * BAND_ELEMS;
  const unsigned short* W = p.gatew + i * D_ * 512;
  const float* bias = p.gateb + i * D_;
  const float* bf = p.bandf[i];
  float* out = p.out + i * BAND_ELEMS;
  const int m0 = blockIdx.x * 128;

  f32x4 acc[4][8];
#pragma unroll
  for (int a = 0; a < 4; ++a)
#pragma unroll
    for (int b = 0; b < 8; ++b) acc[a][b] = (f32x4){0.f, 0.f, 0.f, 0.f};
  gemm_wide<8, true>(A0, A1, W, m0, a_lds, w_lds, acc);

  const int lane = threadIdx.x & 63, wv = threadIdx.x >> 6;
  const int quad = lane >> 4, l15 = lane & 15;
  const int rowbase = m0 + (wv >> 1) * 64 + quad * 4;
  const int colbase = (wv & 1) * 128;
#pragma unroll
  for (int ct = 0; ct < 8; ++ct) {
    const int col = colbase + ct * 16 + l15;
    const float b = bias[col];
#pragma unroll
    for (int rt = 0; rt < 4; ++rt)
#pragma unroll
      for (int r = 0; r < 4; ++r) {
        const size_t idx = (size_t)(rowbase + rt * 16 + r) * 256 + col;
        const float g = 1.f / (1.f + __expf(-(acc[rt][ct][r] + b)));
        const float inj = bf2f(A1[idx]);
        out[idx] = bf[idx] + g * inj;
      }
  }
}

// ============== attention: MFMA scores + softmax + inverted scalar PV =======
__global__ __launch_bounds__(256) void attn_kernel(const unsigned short* __restrict__ q,
                                                   const unsigned short* __restrict__ k,
                                                   const unsigned short* __restrict__ v,
                                                   unsigned short* __restrict__ ctx) {
  __shared__ float plds[4][144][16];    // per-wave P^T: [key][qrow]
  const int wv = threadIdx.x >> 6, lane = threadIdx.x & 63;
  const int quad = lane >> 4, l15 = lane & 15;
  const int bid = blockIdx.x;              // 7*8*16 = 896
  const int n = bid >> 7;
  const int b = (bid >> 4) & 7;
  const int qblk = bid & 15;
  const int t0 = qblk * 64 + wv * 16;
  const int w = 1 << ((0x2344567u >> (4 * n)) & 0xFu);
  const int base = ((n * B_ + b) * T_) * D_;

  int klo_key = t0 - w + 1; if (klo_key < 0) klo_key = 0;
  const int kt_lo = klo_key >> 4;
  const int kt_hi = t0 >> 4;
  const int ntiles = kt_hi - kt_lo + 1;    // <= 9

  bf16x8 qf[8];
  {
    const unsigned short* qr = q + base + (t0 + l15) * D_ + quad * 8;
#pragma unroll
    for (int kc = 0; kc < 8; ++kc) qf[kc] = *(const bf16x8*)(qr + kc * 32);
  }

  f32x4 s[9];
#pragma unroll
  for (int it = 0; it < 9; ++it) {
    if (it < ntiles) {
      const int kt = kt_lo + it;
      const unsigned short* kr = k + base + (kt * 16 + l15) * D_ + quad * 8;
      f32x4 acc = (f32x4){0.f,0.f,0.f,0.f};
#pragma unroll
      for (int kc = 0; kc < 8; ++kc) {
        bf16x8 kf = *(const bf16x8*)(kr + kc * 32);
        acc = __builtin_amdgcn_mfma_f32_16x16x32_bf16(qf[kc], kf, acc, 0, 0, 0);
      }
      s[it] = acc;
    }
  }

#pragma unroll
  for (int r = 0; r < 4; ++r) {
    const int i = t0 + quad * 4 + r;
    float m = -1e30f;
#pragma unroll
    for (int it = 0; it < 9; ++it) {
      if (it < ntiles) {
        const int j = (kt_lo + it) * 16 + l15;
        float val = s[it][r] * 0.0625f;
        val = (j <= i && j > i - w) ? val : -1e30f;
        s[it][r] = val;
        m = fmaxf(m, val);
      }
    }
#pragma unroll
    for (int off = 8; off; off >>= 1) m = fmaxf(m, __shfl_xor(m, off, 64));
    float l = 0.f;
#pragma unroll
    for (int it = 0; it < 9; ++it) {
      if (it < ntiles) {
        float e = __expf(s[it][r] - m);
        s[it][r] = e;
        l += e;
      }
    }
#pragma unroll
    for (int off = 8; off; off >>= 1) l += __shfl_xor(l, off, 64);
    const float inv = 1.f / l;
#pragma unroll
    for (int it = 0; it < 9; ++it)
      if (it < ntiles)
        plds[wv][it * 16 + l15][quad * 4 + r] = s[it][r] * inv;
  }
  __syncthreads();

  const int d0 = lane * 4;
  const int cbase = kt_lo * 16;
  const int njj = ntiles * 16;
  float a0[16], a1[16], a2[16], a3[16];
#pragma unroll
  for (int r = 0; r < 16; ++r) { a0[r] = 0.f; a1[r] = 0.f; a2[r] = 0.f; a3[r] = 0.f; }
  const float* pbase = &plds[wv][0][0];
  const unsigned short* vptr = v + base + (size_t)cbase * D_ + d0;
  for (int jj = 0; jj < njj; ++jj) {
    ushort4 vr = *(const ushort4*)(vptr + (size_t)jj * D_);
    const float v0 = bf2f(vr.x), v1 = bf2f(vr.y), v2 = bf2f(vr.z), v3 = bf2f(vr.w);
    float pv[16];
    *(float4*)(pv + 0)  = *(const float4*)(pbase + jj * 16 + 0);
    *(float4*)(pv + 4)  = *(const float4*)(pbase + jj * 16 + 4);
    *(float4*)(pv + 8)  = *(const float4*)(pbase + jj * 16 + 8);
    *(float4*)(pv + 12) = *(const float4*)(pbase + jj * 16 + 12);
#pragma unroll
    for (int r = 0; r < 16; ++r) {
      a0[r] += pv[r] * v0; a1[r] += pv[r] * v1;
      a2[r] += pv[r] * v2; a3[r] += pv[r] * v3;
    }
  }
#pragma unroll
  for (int r = 0; r < 16; ++r) {
    ushort4 o;
    o.x = f2bf(a0[r]); o.y = f2bf(a1[r]); o.z = f2bf(a2[r]); o.w = f2bf(a3[r]);
    *(ushort4*)(ctx + base + (size_t)(t0 + r) * D_ + d0) = o;
  }
}

// ---------------- other = (sum_n ctx - ctx[3]) / 6 ----------------
__global__ __launch_bounds__(256) void other_kernel(const unsigned short* __restrict__ ctx,
                                                    unsigned short* __restrict__ other) {
  int i = (blockIdx.x * 256 + threadIdx.x) * 4;
  if (i >= BAND_ELEMS) return;
  float s0 = 0.f, s1 = 0.f, s2 = 0.f, s3 = 0.f;
#pragma unroll
  for (int nn = 0; nn < 7; ++nn) {
    if (nn == 3) continue;
    ushort4 c = *(const ushort4*)(ctx + nn * BAND_ELEMS + i);
    s0 += bf2f(c.x); s1 += bf2f(c.y); s2 += bf2f(c.z); s3 += bf2f(c.w);
  }
  const float inv6 = 1.f / 6.f;
  ushort4 o;
  o.x = f2bf(s0 * inv6); o.y = f2bf(s1 * inv6);
  o.z = f2bf(s2 * inv6); o.w = f2bf(s3 * inv6);
  *(ushort4*)(other + i) = o;
}

// ---------------- host launch ----------------
extern "C" void kernel_launch(void* const* d_in, const int* in_sizes, int n_in,
                              void* d_out, int out_size, void* d_ws, size_t ws_size,
                              hipStream_t stream) {
  const float* band[7];
  for (int i = 0; i < 7; ++i) band[i] = (const float*)d_in[i];
  const float* qw = (const float*)d_in[7];   const float* qb = (const float*)d_in[8];
  const float* kw = (const float*)d_in[9];   const float* kb = (const float*)d_in[10];
  const float* vw = (const float*)d_in[11];  const float* vb = (const float*)d_in[12];
  const float* crossw  = (const float*)d_in[13]; const float* crossb  = (const float*)d_in[14];
  const float* crossrw = (const float*)d_in[15]; const float* crossrb = (const float*)d_in[16];
  const float* gatew = (const float*)d_in[17];   const float* gateb = (const float*)d_in[18];
  const float* bridgew = (const float*)d_in[19]; const float* bridgeb = (const float*)d_in[20];

  unsigned short* ws = (unsigned short*)d_ws;
  unsigned short* bands_bf = ws;
  unsigned short* qbf      = bands_bf + 7 * BAND_ELEMS;
  unsigned short* kbf      = qbf + 7 * BAND_ELEMS;
  unsigned short* vbf      = kbf + 7 * BAND_ELEMS;
  unsigned short* ctx      = vbf + 7 * BAND_ELEMS;
  unsigned short* inject   = ctx + 7 * BAND_ELEMS;
  unsigned short* other    = inject + 7 * BAND_ELEMS;
  unsigned short* qw_bf    = other + BAND_ELEMS;
  unsigned short* kw_bf    = qw_bf + 7 * 65536;
  unsigned short* vw_bf    = kw_bf + 7 * 65536;
  unsigned short* crossw_bf  = vw_bf + 7 * 65536;
  unsigned short* crossrw_bf = crossw_bf + 3 * 65536;
  unsigned short* gatew_bf   = crossrw_bf + 3 * 65536;
  unsigned short* bridgew_bf = gatew_bf + 7 * 131072;
  const size_t needed = (size_t)(6 * 7 * BAND_ELEMS + BAND_ELEMS +
                                 3 * 7 * 65536 + 2 * 3 * 65536 + 7 * 131072 + 65536) * 2;
  if (ws_size < needed) return;

  CvtParams cp;
  for (int i = 0; i < 7; ++i) cp.seg[i] = {band[i], bands_bf + i * BAND_ELEMS, BAND_ELEMS};
  cp.seg[7]  = {qw, qw_bf, 7 * 65536};
  cp.seg[8]  = {kw, kw_bf, 7 * 65536};
  cp.seg[9]  = {vw, vw_bf, 7 * 65536};
  cp.seg[10] = {crossw, crossw_bf, 3 * 65536};
  cp.seg[11] = {crossrw, crossrw_bf, 3 * 65536};
  cp.seg[12] = {gatew, gatew_bf, 7 * 131072};
  cp.seg[13] = {bridgew, bridgew_bf, 65536};
  cvt_kernel<<<dim3(BAND_ELEMS / 1024, 14), 256, 0, stream>>>(cp);

  ProjParams pp;
  pp.bands = bands_bf;
  pp.w[0] = qw_bf; pp.w[1] = kw_bf; pp.w[2] = vw_bf;
  pp.bias[0] = qb; pp.bias[1] = kb; pp.bias[2] = vb;
  pp.dst[0] = qbf; pp.dst[1] = kbf; pp.dst[2] = vbf;
  proj_kernel<<<dim3(64, 1, 21), 256, 0, stream>>>(pp);

  attn_kernel<<<dim3(NBAND * B_ * 16), 256, 0, stream>>>(qbf, kbf, vbf, ctx);

  other_kernel<<<dim3(BAND_ELEMS / 1024), 256, 0, stream>>>(ctx, other);

  InjParams ip;
  ip.src[6] = ctx + 0 * BAND_ELEMS; ip.w[6] = crossw_bf + 0 * 65536; ip.bias[6] = crossb + 0 * 256;
  ip.src[5] = ctx + 1 * BAND_ELEMS; ip.w[5] = crossw_bf + 1 * 65536; ip.bias[5] = crossb + 1 * 256;
  ip.src[4] = ctx + 2 * BAND_ELEMS; ip.w[4] = crossw_bf + 2 * 65536; ip.bias[4] = crossb + 2 * 256;
  ip.src[0] = ctx + 6 * BAND_ELEMS; ip.w[0] = crossrw_bf + 0 * 65536; ip.bias[0] = crossrb + 0 * 256;
  ip.src[1] = ctx + 5 * BAND_ELEMS; ip.w[1] = crossrw_bf + 1 * 65536; ip.bias[1] = crossrb + 1 * 256;
  ip.src[2] = ctx + 4 * BAND_ELEMS; ip.w[2] = crossrw_bf + 2 * 65536; ip.bias[2] = crossrb + 2 * 256;
  ip.src[3] = other;                ip.w[3] = bridgew_bf;             ip.bias[3] = bridgeb;
  ip.inject = inject;
  inject_kernel<<<dim3(64, 1, 7), 256, 0, stream>>>(ip);

  GateParams gp;
  gp.bands = bands_bf; gp.inject = inject;
  gp.gatew = gatew_bf; gp.gateb = gateb;
  for (int i = 0; i < 7; ++i) gp.bandf[i] = band[i];
  gp.out = (float*)d_out;
  gate_kernel<<<dim3(64, 1, 7), 256, 0, stream>>>(gp);
}